// Round 3
// baseline (556.820 us; speedup 1.0000x reference)
//
#include <hip/hip_runtime.h>

// Problem constants
#define B_   8
#define T1_  4
#define TP_  3
#define TF_  4
#define C_   256
#define HW_  4096

// Workspace layout (bytes)
#define OFF_FP     0ull          // feature_p bf16: 8*4*256*4096*2 = 67108864
#define OFF_PMAXK  67108864ull   // fp pool max keys (uint) B*TP*C = 24576 B
#define OFF_PSUM   67133440ull   // fp pool sums (float)              24576 B
#define OFF_RMAXK  67158016ull   // raw pool max keys (uint) B*C      8192 B
#define OFF_RSUM   67166208ull   // raw pool sum (float)              8192 B
#define OFF_AW     67231744ull   // attn_w: B*TF*TP floats             384 B
#define OFF_WBF    67232128ull   // Wbf bf16 (scale-folded) 256*256*2 = 131072 B
#define OFF_SHIFT  67363200ull   // shift: 256 floats                  1024 B

typedef __attribute__((ext_vector_type(8))) short bf16x8;
typedef __attribute__((ext_vector_type(4))) float f32x4;

__device__ __forceinline__ unsigned short f2bf(float f) {
    unsigned int u = __float_as_uint(f);
    u += 0x7fffu + ((u >> 16) & 1u);        // RNE
    return (unsigned short)(u >> 16);
}
__device__ __forceinline__ unsigned int fkey(float x) {
    unsigned int b = __float_as_uint(x);
    return (b & 0x80000000u) ? ~b : (b | 0x80000000u);
}
__device__ __forceinline__ float funkey(unsigned int k) {
    unsigned int b = (k & 0x80000000u) ? (k ^ 0x80000000u) : ~k;
    return __uint_as_float(b);
}
__device__ __forceinline__ float silu_f(float x) { return x / (1.0f + __expf(-x)); }

__device__ __forceinline__ void dec8(uint4 u, float* f) {
    f[0] = __uint_as_float(u.x << 16); f[1] = __uint_as_float(u.x & 0xffff0000u);
    f[2] = __uint_as_float(u.y << 16); f[3] = __uint_as_float(u.y & 0xffff0000u);
    f[4] = __uint_as_float(u.z << 16); f[5] = __uint_as_float(u.z & 0xffff0000u);
    f[6] = __uint_as_float(u.w << 16); f[7] = __uint_as_float(u.w & 0xffff0000u);
}

// ---------------- kprep: Wbf[o][c] = bf16(W[o][c] * bn_scale[o]); shift[o] ----
__global__ __launch_bounds__(256) void kprep(const float* __restrict__ Wc,
                                             const float* __restrict__ gamma,
                                             const float* __restrict__ beta,
                                             const float* __restrict__ mean,
                                             const float* __restrict__ var,
                                             unsigned short* __restrict__ Wbf,
                                             float* __restrict__ shift) {
    const int tid = threadIdx.x;
    const int idx = blockIdx.x * 1024 + tid * 4;   // grid=64
    const int o = idx >> 8;
    const float sc = gamma[o] * rsqrtf(var[o] + 1e-3f);
    float4 v = *(const float4*)(Wc + idx);
    ushort4 u;
    u.x = f2bf(v.x * sc); u.y = f2bf(v.y * sc);
    u.z = f2bf(v.z * sc); u.w = f2bf(v.w * sc);
    *(ushort4*)(Wbf + idx) = u;
    if (blockIdx.x == 0) {
        float s2 = gamma[tid] * rsqrtf(var[tid] + 1e-3f);
        shift[tid] = beta[tid] - mean[tid] * s2;
    }
}

// ---------------- K1 v3: single-barrier block; fused raw pooling (t==3) -------
// Stage the FULL B tile (64 hw x 256 k, bf16) in LDS with no barriers between
// batches (deep MLP, vmcnt FIFO lets later batches stay in flight), ONE
// __syncthreads, then 8 MFMA k-steps back-to-back. A frags double-buffered
// from global Wbf (L2-hot).
__global__ __launch_bounds__(256) void k1_conv(
    const float* __restrict__ feature, const unsigned short* __restrict__ Wbf,
    const float* __restrict__ shift,
    unsigned short* __restrict__ fp_out,
    unsigned int* __restrict__ pmaxk, float* __restrict__ psum,
    unsigned int* __restrict__ rmaxk, float* __restrict__ rsum) {
    __shared__ __align__(16) unsigned short lds_b[64 * 264];   // 33792 B, pitch 264
    __shared__ float s_shift[256];

    const int tid   = threadIdx.x;
    const int bt    = blockIdx.x >> 6;       // (b,t) 0..31
    const int hwblk = blockIdx.x & 63;
    const int b = bt >> 2, t = bt & 3;
    const int hw0 = hwblk * 64;
    const int lane = tid & 63;
    const int wave = tid >> 6;               // 0..3 = o-quadrant
    const int q = lane >> 4;
    const int col = lane & 15;

    s_shift[tid] = shift[tid];
    const float* Fb = feature + (size_t)bt * C_ * HW_;

    // ---- staging: 8 batches x 8 k's per thread, no barriers between ----
    #pragma unroll
    for (int s = 0; s < 8; ++s) {
        const int cb = s * 32 + wave * 8;
        float fv[8];
        #pragma unroll
        for (int j = 0; j < 8; ++j)
            fv[j] = Fb[(size_t)(cb + j) * HW_ + hw0 + lane];
        if (t == 3) {    // fused raw pool of feature[:,3] (block-uniform branch)
            #pragma unroll
            for (int j = 0; j < 8; ++j) {
                float mx = fv[j], sm = fv[j];
                #pragma unroll
                for (int d = 1; d < 64; d <<= 1) {
                    mx = fmaxf(mx, __shfl_xor(mx, d));
                    sm += __shfl_xor(sm, d);
                }
                if (lane == 0) {
                    atomicMax(&rmaxk[b * C_ + cb + j], fkey(mx));
                    atomicAdd(&rsum[b * C_ + cb + j], sm);
                }
            }
        }
        uint4 pk;
        pk.x = ((unsigned)f2bf(fv[1]) << 16) | f2bf(fv[0]);
        pk.y = ((unsigned)f2bf(fv[3]) << 16) | f2bf(fv[2]);
        pk.z = ((unsigned)f2bf(fv[5]) << 16) | f2bf(fv[4]);
        pk.w = ((unsigned)f2bf(fv[7]) << 16) | f2bf(fv[6]);
        *(uint4*)&lds_b[lane * 264 + cb] = pk;
    }
    __syncthreads();   // the ONLY barrier

    // ---- MFMA phase: 8 k-steps, A double-buffered from global ----
    f32x4 acc[4][4] = {};
    bf16x8 afr[2][4];
    #pragma unroll
    for (int mi = 0; mi < 4; ++mi)
        afr[0][mi] = *(const bf16x8*)(Wbf + (size_t)(wave * 64 + mi * 16 + col) * 256 + q * 8);
    #pragma unroll
    for (int it = 0; it < 8; ++it) {
        const int cur = it & 1;
        if (it < 7) {
            #pragma unroll
            for (int mi = 0; mi < 4; ++mi)
                afr[cur ^ 1][mi] = *(const bf16x8*)(Wbf + (size_t)(wave * 64 + mi * 16 + col) * 256
                                                    + (it + 1) * 32 + q * 8);
        }
        bf16x8 bfr[4];
        #pragma unroll
        for (int ni = 0; ni < 4; ++ni)
            bfr[ni] = *(const bf16x8*)&lds_b[(ni * 16 + col) * 264 + it * 32 + q * 8];
        #pragma unroll
        for (int mi = 0; mi < 4; ++mi)
            #pragma unroll
            for (int ni = 0; ni < 4; ++ni)
                acc[mi][ni] = __builtin_amdgcn_mfma_f32_16x16x32_bf16(afr[cur][mi], bfr[ni], acc[mi][ni], 0, 0, 0);
    }

    // ---- epilogue: + shift, silu, store bf16, per-o pool partials (t<3) ----
    unsigned short* fpo = fp_out + (size_t)bt * C_ * HW_;
    float pmx_r[16], psm_r[16];
    #pragma unroll
    for (int mi = 0; mi < 4; ++mi) {
        #pragma unroll
        for (int r = 0; r < 4; ++r) {
            const int o = wave * 64 + mi * 16 + q * 4 + r;
            const float sh = s_shift[o];
            float mx = -3.4e38f, sm = 0.0f;
            #pragma unroll
            for (int ni = 0; ni < 4; ++ni) {
                float x = acc[mi][ni][r] + sh;
                float s = silu_f(x);
                fpo[(size_t)o * HW_ + hw0 + ni * 16 + col] = f2bf(s);
                mx = fmaxf(mx, s);
                sm += s;
            }
            pmx_r[mi * 4 + r] = mx;
            psm_r[mi * 4 + r] = sm;
        }
    }
    if (t < 3) {                              // block-uniform branch
        // 16 partials for one o live in lanes q*16+0..15 -> shuffle-reduce
        #pragma unroll
        for (int i = 0; i < 16; ++i) {
            float m = pmx_r[i], s = psm_r[i];
            #pragma unroll
            for (int d = 1; d < 16; d <<= 1) {
                m = fmaxf(m, __shfl_xor(m, d));
                s += __shfl_xor(s, d);
            }
            pmx_r[i] = m; psm_r[i] = s;
        }
        if (col == 0) {
            #pragma unroll
            for (int mi = 0; mi < 4; ++mi)
                #pragma unroll
                for (int r = 0; r < 4; ++r) {
                    const int o = wave * 64 + mi * 16 + q * 4 + r;
                    atomicMax(&pmaxk[(b * 3 + t) * C_ + o], fkey(pmx_r[mi * 4 + r]));
                    atomicAdd(&psum[(b * 3 + t) * C_ + o], psm_r[mi * 4 + r]);
                }
        }
    }
}

// ---------------- K2 fused: pools -> attn_in -> q/k -> attn_w (per batch b) ---
__global__ __launch_bounds__(448) void k2_fused(
    const float* __restrict__ past_tc, const float* __restrict__ fut_tc,
    const float* __restrict__ w_tc, const float* __restrict__ b_tc,
    const float* __restrict__ w_in, const float* __restrict__ b_in,
    const float* __restrict__ w_q, const float* __restrict__ b_q,
    const float* __restrict__ w_k, const float* __restrict__ b_k,
    const unsigned int* __restrict__ pmaxk, const float* __restrict__ psum,
    const unsigned int* __restrict__ rmaxk, const float* __restrict__ rsum,
    float* __restrict__ aw) {
    __shared__ float s_pool[7][512];
    __shared__ float s_avec[7][256];
    __shared__ float s_qk[7][256];
    const int b = blockIdx.x;
    const int w = threadIdx.x >> 6;      // 0..6: 0-2 = p-side t, 3-6 = f-side f
    const int lane = threadIdx.x & 63;
    const bool pside = (w < 3);

    #pragma unroll
    for (int e = 0; e < 8; ++e) {
        int c = lane * 8 + e;            // 0..511
        float v;
        if (c < 256) {
            v = pside ? funkey(pmaxk[(b * 3 + w) * C_ + c]) : funkey(rmaxk[b * C_ + c]);
        } else {
            int cc = c - 256;
            v = (pside ? psum[(b * 3 + w) * C_ + cc] : rsum[b * C_ + cc]) * (1.0f / 4096.0f);
        }
        s_pool[w][c] = v;
    }
    __syncthreads();
    const float tcin = pside ? past_tc[b * 3 + w] : fut_tc[b * 4 + (w - 3)];
    #pragma unroll
    for (int i = 0; i < 4; ++i) {
        const int o = i * 64 + lane;
        float s = b_in[o];
        const float* wr = w_in + (size_t)o * 512;
        #pragma unroll 8
        for (int c = 0; c < 512; ++c) s += wr[c] * s_pool[w][c];
        float tc = tanhf(tcin * w_tc[o] + b_tc[o]);
        s_avec[w][o] = silu_f(s) + tc;
    }
    __syncthreads();
    #pragma unroll
    for (int i = 0; i < 4; ++i) {
        const int o = i * 64 + lane;
        const float* wm = (pside ? w_k : w_q) + (size_t)o * 256;
        float s = pside ? b_k[o] : b_q[o];
        #pragma unroll 8
        for (int c = 0; c < 256; ++c) s += wm[c] * s_avec[w][c];
        s_qk[w][o] = s;
    }
    __syncthreads();
    if (w < 4) {                          // wave w handles f=w, all 3 p's
        #pragma unroll
        for (int p = 0; p < 3; ++p) {
            float part = 0.0f;
            #pragma unroll
            for (int j = 0; j < 4; ++j)
                part += s_qk[3 + w][lane + 64 * j] * s_qk[p][lane + 64 * j];
            #pragma unroll
            for (int d = 1; d < 64; d <<= 1) part += __shfl_xor(part, d);
            if (lane == 0) aw[b * 12 + w * 3 + p] = part * 0.5f;   // / sqrt(TF=4)
        }
    }
}

// ---------------- K3: out = last + (p_attn/TP) * sum_p aw*(fp3 - fp_p) --------
__global__ __launch_bounds__(256) void k3_out(
    const float* __restrict__ feature, const unsigned short* __restrict__ fp,
    const float* __restrict__ aw, const float* __restrict__ p_attn,
    float* __restrict__ out) {
    const int idx = blockIdx.x;              // 4096 = B * C * 2
    const int b = idx >> 9;
    const int c = (idx >> 1) & 255;
    const int half = idx & 1;
    const int hw = half * 2048 + threadIdx.x * 8;

    float a[12];
    #pragma unroll
    for (int i = 0; i < 12; ++i) a[i] = aw[b * 12 + i];
    const float pa = p_attn[c] * (1.0f / 3.0f);

    const size_t ts = (size_t)C_ * HW_;
    const size_t base = ((size_t)(b * 4) * C_ + c) * HW_ + hw;

    uint4 u0 = *(const uint4*)(fp + base);
    uint4 u1 = *(const uint4*)(fp + base + ts);
    uint4 u2 = *(const uint4*)(fp + base + 2 * ts);
    uint4 u3 = *(const uint4*)(fp + base + 3 * ts);
    float4 l0 = *(const float4*)(feature + base + 3 * ts);
    float4 l1 = *(const float4*)(feature + base + 3 * ts + 4);

    float f0[8], f1[8], f2[8], f3[8];
    dec8(u0, f0); dec8(u1, f1); dec8(u2, f2); dec8(u3, f3);
    float lastv[8] = {l0.x, l0.y, l0.z, l0.w, l1.x, l1.y, l1.z, l1.w};

    float ov[4][8];
    #pragma unroll
    for (int e = 0; e < 8; ++e) {
        float d0 = f3[e] - f0[e];
        float d1 = f3[e] - f1[e];
        float d2 = f3[e] - f2[e];
        #pragma unroll
        for (int f = 0; f < 4; ++f) {
            float at = a[f * 3 + 0] * d0 + a[f * 3 + 1] * d1 + a[f * 3 + 2] * d2;
            ov[f][e] = lastv[e] + at * pa;
        }
    }
    #pragma unroll
    for (int f = 0; f < 4; ++f) {
        size_t ob = ((size_t)(b * 4 + f) * C_ + c) * HW_ + hw;
        *(float4*)(out + ob)     = make_float4(ov[f][0], ov[f][1], ov[f][2], ov[f][3]);
        *(float4*)(out + ob + 4) = make_float4(ov[f][4], ov[f][5], ov[f][6], ov[f][7]);
    }
}

extern "C" void kernel_launch(void* const* d_in, const int* in_sizes, int n_in,
                              void* d_out, int out_size, void* d_ws, size_t ws_size,
                              hipStream_t stream) {
    const float* feature = (const float*)d_in[0];
    const float* past_tc = (const float*)d_in[1];
    const float* fut_tc  = (const float*)d_in[2];
    const float* w_tc    = (const float*)d_in[3];
    const float* b_tc    = (const float*)d_in[4];
    const float* w_in    = (const float*)d_in[5];
    const float* b_in    = (const float*)d_in[6];
    const float* conv_w  = (const float*)d_in[7];
    const float* gamma   = (const float*)d_in[8];
    const float* beta    = (const float*)d_in[9];
    const float* mean    = (const float*)d_in[10];
    const float* var     = (const float*)d_in[11];
    const float* w_q     = (const float*)d_in[12];
    const float* b_q     = (const float*)d_in[13];
    const float* w_k     = (const float*)d_in[14];
    const float* b_k     = (const float*)d_in[15];
    const float* p_attn  = (const float*)d_in[16];

    char* ws = (char*)d_ws;
    unsigned short* fp  = (unsigned short*)(ws + OFF_FP);
    unsigned int* pmaxk = (unsigned int*)(ws + OFF_PMAXK);
    float* psum = (float*)(ws + OFF_PSUM);
    unsigned int* rmaxk = (unsigned int*)(ws + OFF_RMAXK);
    float* rsum = (float*)(ws + OFF_RSUM);
    float* aw   = (float*)(ws + OFF_AW);
    unsigned short* Wbf = (unsigned short*)(ws + OFF_WBF);
    float* shift = (float*)(ws + OFF_SHIFT);

    // zero all pool accumulators (maxkey 0 == below all finite floats; sums 0.0f)
    hipMemsetAsync(ws + OFF_PMAXK, 0, 65536, stream);

    kprep<<<64, 256, 0, stream>>>(conv_w, gamma, beta, mean, var, Wbf, shift);
    k1_conv<<<B_ * T1_ * 64, 256, 0, stream>>>(feature, Wbf, shift, fp,
                                               pmaxk, psum, rmaxk, rsum);
    k2_fused<<<B_, 448, 0, stream>>>(past_tc, fut_tc, w_tc, b_tc, w_in, b_in,
                                     w_q, b_q, w_k, b_k, pmaxk, psum, rmaxk, rsum, aw);
    k3_out<<<B_ * C_ * 2, 256, 0, stream>>>(feature, fp, aw, p_attn, (float*)d_out);
}